// Round 1
// baseline (732.784 us; speedup 1.0000x reference)
//
#include <hip/hip_runtime.h>
#include <hip/hip_bf16.h>
#include <cstddef>

#define BS   16
#define SLEN 512
#define DM   512
#define NH   8
#define DK   64
#define DC   21

// ---------------------------------------------------------------------------
// Tiled fp32 GEMM: C[m][n] = sum_k X[m][k]*W[n][k] + bias[n]
// X: [M x 512] row-major, W: [512 x 512] row-major (we need X @ W^T).
// per_head=1: write to per-head layout out[((b*8+h)*512+s)*64+d],
//             where m=b*512+s, n=h*64+d (n-tile 64 == one head).
// per_head=0: write standard out[m*512+n].
// BM=BN=64, BK=32, 256 threads, 4x4 per thread. LDS stored k-major
// (transposed) so inner loop does two b128 reads per 16 FMA.
// ---------------------------------------------------------------------------
__global__ __launch_bounds__(256) void gemm512(
    const float* __restrict__ X, const float* __restrict__ W,
    const float* __restrict__ bias, float* __restrict__ out, int per_head)
{
    __shared__ float As[32][68];   // [kk][m_local]
    __shared__ float Ws[32][68];   // [kk][n_local]
    const int tid = threadIdx.x;
    const int m0 = blockIdx.y * 64;
    const int n0 = blockIdx.x * 64;
    const int lr = tid >> 2;            // 0..63 (tile row)
    const int lc = (tid & 3) * 8;       // 0,8,16,24 (k offset)
    const int ty = tid >> 4;            // 0..15 (m group)
    const int tx = tid & 15;            // 0..15 (n group)

    float acc[4][4] = {};

    for (int k0 = 0; k0 < 512; k0 += 32) {
        const float4 a0 = *(const float4*)&X[(size_t)(m0 + lr) * 512 + k0 + lc];
        const float4 a1 = *(const float4*)&X[(size_t)(m0 + lr) * 512 + k0 + lc + 4];
        const float4 w0 = *(const float4*)&W[(size_t)(n0 + lr) * 512 + k0 + lc];
        const float4 w1 = *(const float4*)&W[(size_t)(n0 + lr) * 512 + k0 + lc + 4];
        __syncthreads();
        As[lc + 0][lr] = a0.x; As[lc + 1][lr] = a0.y;
        As[lc + 2][lr] = a0.z; As[lc + 3][lr] = a0.w;
        As[lc + 4][lr] = a1.x; As[lc + 5][lr] = a1.y;
        As[lc + 6][lr] = a1.z; As[lc + 7][lr] = a1.w;
        Ws[lc + 0][lr] = w0.x; Ws[lc + 1][lr] = w0.y;
        Ws[lc + 2][lr] = w0.z; Ws[lc + 3][lr] = w0.w;
        Ws[lc + 4][lr] = w1.x; Ws[lc + 5][lr] = w1.y;
        Ws[lc + 6][lr] = w1.z; Ws[lc + 7][lr] = w1.w;
        __syncthreads();
#pragma unroll
        for (int kk = 0; kk < 32; ++kk) {
            const float4 av = *(const float4*)&As[kk][ty * 4];
            const float4 wv = *(const float4*)&Ws[kk][tx * 4];
            const float aa[4] = {av.x, av.y, av.z, av.w};
            const float ww[4] = {wv.x, wv.y, wv.z, wv.w};
#pragma unroll
            for (int i = 0; i < 4; ++i)
#pragma unroll
                for (int j = 0; j < 4; ++j)
                    acc[i][j] += aa[i] * ww[j];
        }
    }

    const float4 bv = *(const float4*)&bias[n0 + tx * 4];
    const float bb4[4] = {bv.x, bv.y, bv.z, bv.w};
#pragma unroll
    for (int i = 0; i < 4; ++i) {
        const int m = m0 + ty * 4 + i;
        float4 res;
        res.x = acc[i][0] + bb4[0];
        res.y = acc[i][1] + bb4[1];
        res.z = acc[i][2] + bb4[2];
        res.w = acc[i][3] + bb4[3];
        if (per_head) {
            const int bidx = m >> 9;
            const int s = m & 511;
            const int h = n0 >> 6;          // n-tile == head
            const int d = tx * 4;
            *(float4*)&out[((size_t)(bidx * NH + h) * SLEN + s) * DK + d] = res;
        } else {
            *(float4*)&out[(size_t)m * 512 + n0 + tx * 4] = res;
        }
    }
}

// ---------------------------------------------------------------------------
// Bias: bias[b,h,q,k] = sum_c dtw[b,c,q,k]*Wd[h,c] + bd[h]
// One block per (q,b); thread = k. 21 reads -> 8 outputs (dtw read once).
// Writes into the attn region of d_out (staging; attn kernel overwrites).
// ---------------------------------------------------------------------------
__global__ __launch_bounds__(512) void bias_kernel(
    const float* __restrict__ dtw, const float* __restrict__ Wd,
    const float* __restrict__ bd, float* __restrict__ bias_out)
{
    __shared__ float wdl[NH * DC];
    __shared__ float bdl[NH];
    const int k = threadIdx.x;
    const int q = blockIdx.x;
    const int b = blockIdx.y;
    if (k < NH * DC) wdl[k] = Wd[k];
    if (k < NH) bdl[k] = bd[k];
    __syncthreads();

    float acc[NH];
#pragma unroll
    for (int h = 0; h < NH; ++h) acc[h] = bdl[h];

    const float* p = dtw + ((size_t)b * DC * SLEN + q) * SLEN + k;
#pragma unroll
    for (int c = 0; c < DC; ++c) {
        const float x = p[(size_t)c * SLEN * SLEN];
#pragma unroll
        for (int h = 0; h < NH; ++h) acc[h] += x * wdl[h * DC + c];
    }
#pragma unroll
    for (int h = 0; h < NH; ++h)
        bias_out[((size_t)(b * NH + h) * SLEN + q) * SLEN + k] = acc[h];
}

// ---------------------------------------------------------------------------
// Fused attention: per (b,h,16-q-row tile):
//   scores = QK^T (raw) -> LDS; s = raw*0.125 + bias(global, staged);
//   softmax in-wave (16 lanes/row); write attn (overwrites bias);
//   PV into concat layout [b][s][h*64+d].
// ---------------------------------------------------------------------------
#define QR 16
__global__ __launch_bounds__(256) void attn_fused(
    const float* __restrict__ qg, const float* __restrict__ kg,
    const float* __restrict__ vg, float* __restrict__ attn,
    float* __restrict__ concat)
{
    __shared__ float Qs[QR][64];
    __shared__ float KV[64][68];      // K-tile transposed, then V-tile natural
    __shared__ float Sc[QR][516];
    __shared__ float rowinv[QR];

    const int tid = threadIdx.x;
    const int q0 = blockIdx.x * QR;
    const int h = blockIdx.y;
    const int b = blockIdx.z;
    const int bh = b * NH + h;

    const float* qbase = qg + ((size_t)bh * SLEN + q0) * DK;
    const float* kbase = kg + (size_t)bh * SLEN * DK;
    const float* vbase = vg + (size_t)bh * SLEN * DK;
    float* attn_base = attn + ((size_t)bh * SLEN + q0) * SLEN;

    // load Q tile (16x64)
    {
        const int r = tid >> 4, c = (tid & 15) * 4;
        *(float4*)&Qs[r][c] = *(const float4*)&qbase[r * 64 + c];
    }

    const int sr = tid >> 4;    // q-row 0..15
    const int scg = tid & 15;   // k group (4 cols)

    // ---- scores: raw QK^T ----
    for (int kt = 0; kt < 512; kt += 64) {
        const int kr = tid >> 2;
        const int dc = (tid & 3) * 16;
        const float* src = &kbase[(size_t)(kt + kr) * 64 + dc];
        const float4 x0 = *(const float4*)&src[0];
        const float4 x1 = *(const float4*)&src[4];
        const float4 x2 = *(const float4*)&src[8];
        const float4 x3 = *(const float4*)&src[12];
        __syncthreads();                 // prev-tile compute done (also fences Qs store on kt=0)
        KV[dc + 0][kr] = x0.x; KV[dc + 1][kr] = x0.y; KV[dc + 2][kr] = x0.z; KV[dc + 3][kr] = x0.w;
        KV[dc + 4][kr] = x1.x; KV[dc + 5][kr] = x1.y; KV[dc + 6][kr] = x1.z; KV[dc + 7][kr] = x1.w;
        KV[dc + 8][kr] = x2.x; KV[dc + 9][kr] = x2.y; KV[dc +10][kr] = x2.z; KV[dc +11][kr] = x2.w;
        KV[dc +12][kr] = x3.x; KV[dc +13][kr] = x3.y; KV[dc +14][kr] = x3.z; KV[dc +15][kr] = x3.w;
        __syncthreads();

        float a0 = 0.f, a1 = 0.f, a2 = 0.f, a3 = 0.f;
#pragma unroll
        for (int d = 0; d < 64; ++d) {
            const float qv = Qs[sr][d];
            const float4 kv = *(const float4*)&KV[d][scg * 4];
            a0 += qv * kv.x; a1 += qv * kv.y; a2 += qv * kv.z; a3 += qv * kv.w;
        }
        *(float4*)&Sc[sr][kt + scg * 4] = make_float4(a0, a1, a2, a3);
    }
    __syncthreads();

    // ---- add bias (staged in attn region) ----
    for (int idx = tid; idx < QR * 512; idx += 256) {
        const int r = idx >> 9, c = idx & 511;
        Sc[r][c] = Sc[r][c] * 0.125f + attn_base[(size_t)r * 512 + c];
    }
    __syncthreads();

    // ---- softmax (16 lanes per row) ----
    {
        const int r = tid >> 4, lane = tid & 15;
        float m = -1e30f;
#pragma unroll
        for (int i = 0; i < 32; ++i) m = fmaxf(m, Sc[r][lane + 16 * i]);
#pragma unroll
        for (int off = 8; off; off >>= 1) m = fmaxf(m, __shfl_xor(m, off, 16));
        float sum = 0.f;
#pragma unroll
        for (int i = 0; i < 32; ++i) {
            const int c = lane + 16 * i;
            const float e = __expf(Sc[r][c] - m);
            Sc[r][c] = e;                 // keep unnormalized; fold inv later
            sum += e;
        }
#pragma unroll
        for (int off = 8; off; off >>= 1) sum += __shfl_xor(sum, off, 16);
        if (lane == 0) rowinv[r] = 1.0f / sum;
    }
    __syncthreads();

    // ---- write attn (overwrites staged bias) ----
    for (int idx = tid; idx < QR * 512; idx += 256) {
        const int r = idx >> 9, c = idx & 511;
        attn_base[(size_t)r * 512 + c] = Sc[r][c] * rowinv[r];
    }

    // ---- PV ----
    float acc[4] = {0.f, 0.f, 0.f, 0.f};
    const int pr = tid >> 4;         // q-row
    const int pd = (tid & 15) * 4;   // d offset
    for (int kt = 0; kt < 512; kt += 64) {
        const int kr = tid >> 2;
        const int dc = (tid & 3) * 16;
        const float* src = &vbase[(size_t)(kt + kr) * 64 + dc];
        const float4 x0 = *(const float4*)&src[0];
        const float4 x1 = *(const float4*)&src[4];
        const float4 x2 = *(const float4*)&src[8];
        const float4 x3 = *(const float4*)&src[12];
        __syncthreads();                // everyone done reading KV (scores) / prev V tile
        *(float4*)&KV[kr][dc + 0] = x0;
        *(float4*)&KV[kr][dc + 4] = x1;
        *(float4*)&KV[kr][dc + 8] = x2;
        *(float4*)&KV[kr][dc +12] = x3;
        __syncthreads();
#pragma unroll
        for (int kk = 0; kk < 64; ++kk) {
            const float p = Sc[pr][kt + kk];
            const float4 vv = *(const float4*)&KV[kk][pd];
            acc[0] += p * vv.x; acc[1] += p * vv.y;
            acc[2] += p * vv.z; acc[3] += p * vv.w;
        }
    }
    const float inv = rowinv[pr];
    float4 res = make_float4(acc[0] * inv, acc[1] * inv, acc[2] * inv, acc[3] * inv);
    *(float4*)&concat[((size_t)(b * SLEN + q0 + pr)) * DM + h * 64 + pd] = res;
}

// ---------------------------------------------------------------------------
extern "C" void kernel_launch(void* const* d_in, const int* in_sizes, int n_in,
                              void* d_out, int out_size, void* d_ws, size_t ws_size,
                              hipStream_t stream)
{
    const float* Q   = (const float*)d_in[0];
    const float* K   = (const float*)d_in[1];
    const float* V   = (const float*)d_in[2];
    // d_in[3] = G (unused by reference)
    const float* dtw = (const float*)d_in[4];
    const float* Wq  = (const float*)d_in[5];
    const float* bq  = (const float*)d_in[6];
    const float* Wk  = (const float*)d_in[7];
    const float* bk  = (const float*)d_in[8];
    const float* Wv  = (const float*)d_in[9];
    const float* bv  = (const float*)d_in[10];
    const float* Wd  = (const float*)d_in[11];
    const float* bd  = (const float*)d_in[12];
    const float* Wo  = (const float*)d_in[13];
    const float* bo  = (const float*)d_in[14];

    float* out  = (float*)d_out;                       // [16,512,512]
    float* attn = out + (size_t)BS * SLEN * DM;        // [16,8,512,512]

    float* ws = (float*)d_ws;
    const size_t PHS = (size_t)BS * NH * SLEN * DK;    // 4,194,304
    float* qb = ws;
    float* kb = qb + PHS;
    float* vb = kb + PHS;
    float* cb = vb + PHS;                              // concat [16,512,512]

    const dim3 gemm_grid(8, 128);

    // QKV projections -> per-head layout
    gemm512<<<gemm_grid, 256, 0, stream>>>(Q, Wq, bq, qb, 1);
    gemm512<<<gemm_grid, 256, 0, stream>>>(K, Wk, bk, kb, 1);
    gemm512<<<gemm_grid, 256, 0, stream>>>(V, Wv, bv, vb, 1);

    // DTW bias -> staged into attn region of d_out
    bias_kernel<<<dim3(SLEN, BS), 512, 0, stream>>>(dtw, Wd, bd, attn);

    // fused scores+softmax+PV; writes attn (final) + concat
    attn_fused<<<dim3(SLEN / QR, NH, BS), 256, 0, stream>>>(qb, kb, vb, attn, cb);

    // output projection
    gemm512<<<gemm_grid, 256, 0, stream>>>(cb, Wo, bo, out, 0);
}

// Round 2
// 480.583 us; speedup vs baseline: 1.5248x; 1.5248x over previous
//
#include <hip/hip_runtime.h>
#include <hip/hip_bf16.h>
#include <cstddef>
#include <cstdint>

#define BS   16
#define SLEN 512
#define DM   512
#define NH   8
#define DK   64
#define DC   21

typedef __attribute__((ext_vector_type(8))) short short8;   // 8 bf16 = 4 VGPR
typedef __attribute__((ext_vector_type(4))) float f32x4;

__device__ inline unsigned pack_bf16(float a, float b) {
    unsigned ua = __builtin_bit_cast(unsigned, a);
    unsigned ub = __builtin_bit_cast(unsigned, b);
    ua = (ua + 0x7fffu + ((ua >> 16) & 1u)) >> 16;          // RNE
    ub = (ub + 0x7fffu + ((ub >> 16) & 1u)) >> 16;
    return ua | (ub << 16);
}

// ---------------------------------------------------------------------------
// Tiled fp32 GEMM: C[m][n] = sum_k X[m][k]*W[n][k] + bias[n]
// mode 0: fp32 out[m*512+n]            (output projection)
// mode 1: bf16 per-head out[bh][s][64] (q, k)
// mode 2: bf16 transposed out[bh][64][s] (v)
// ---------------------------------------------------------------------------
__global__ __launch_bounds__(256) void gemm512(
    const float* __restrict__ X, const float* __restrict__ W,
    const float* __restrict__ bias, void* __restrict__ outv, int mode)
{
    __shared__ float As[32][68];
    __shared__ float Ws[32][68];
    const int tid = threadIdx.x;
    const int m0 = blockIdx.y * 64;
    const int n0 = blockIdx.x * 64;
    const int lr = tid >> 2;
    const int lc = (tid & 3) * 8;
    const int ty = tid >> 4;
    const int tx = tid & 15;

    float acc[4][4] = {};

    for (int k0 = 0; k0 < 512; k0 += 32) {
        const float4 a0 = *(const float4*)&X[(size_t)(m0 + lr) * 512 + k0 + lc];
        const float4 a1 = *(const float4*)&X[(size_t)(m0 + lr) * 512 + k0 + lc + 4];
        const float4 w0 = *(const float4*)&W[(size_t)(n0 + lr) * 512 + k0 + lc];
        const float4 w1 = *(const float4*)&W[(size_t)(n0 + lr) * 512 + k0 + lc + 4];
        __syncthreads();
        As[lc + 0][lr] = a0.x; As[lc + 1][lr] = a0.y;
        As[lc + 2][lr] = a0.z; As[lc + 3][lr] = a0.w;
        As[lc + 4][lr] = a1.x; As[lc + 5][lr] = a1.y;
        As[lc + 6][lr] = a1.z; As[lc + 7][lr] = a1.w;
        Ws[lc + 0][lr] = w0.x; Ws[lc + 1][lr] = w0.y;
        Ws[lc + 2][lr] = w0.z; Ws[lc + 3][lr] = w0.w;
        Ws[lc + 4][lr] = w1.x; Ws[lc + 5][lr] = w1.y;
        Ws[lc + 6][lr] = w1.z; Ws[lc + 7][lr] = w1.w;
        __syncthreads();
#pragma unroll
        for (int kk = 0; kk < 32; ++kk) {
            const float4 av = *(const float4*)&As[kk][ty * 4];
            const float4 wv = *(const float4*)&Ws[kk][tx * 4];
            const float aa[4] = {av.x, av.y, av.z, av.w};
            const float ww[4] = {wv.x, wv.y, wv.z, wv.w};
#pragma unroll
            for (int i = 0; i < 4; ++i)
#pragma unroll
                for (int j = 0; j < 4; ++j)
                    acc[i][j] += aa[i] * ww[j];
        }
    }

    const float4 bv = *(const float4*)&bias[n0 + tx * 4];
    const float bb4[4] = {bv.x, bv.y, bv.z, bv.w};

    if (mode == 0) {
        float* out = (float*)outv;
#pragma unroll
        for (int i = 0; i < 4; ++i) {
            const int m = m0 + ty * 4 + i;
            float4 res;
            res.x = acc[i][0] + bb4[0];
            res.y = acc[i][1] + bb4[1];
            res.z = acc[i][2] + bb4[2];
            res.w = acc[i][3] + bb4[3];
            *(float4*)&out[(size_t)m * 512 + n0 + tx * 4] = res;
        }
    } else if (mode == 1) {
        // bf16 per-head [bh][s][64]
        ushort* out = (ushort*)outv;
        const int h = n0 >> 6;
#pragma unroll
        for (int i = 0; i < 4; ++i) {
            const int m = m0 + ty * 4 + i;
            const int bidx = m >> 9;
            const int s = m & 511;
            uint2 p;
            p.x = pack_bf16(acc[i][0] + bb4[0], acc[i][1] + bb4[1]);
            p.y = pack_bf16(acc[i][2] + bb4[2], acc[i][3] + bb4[3]);
            *(uint2*)&out[((size_t)(bidx * NH + h) * SLEN + s) * DK + tx * 4] = p;
        }
    } else {
        // bf16 transposed per-head [bh][64][s]
        ushort* out = (ushort*)outv;
        const int h = n0 >> 6;
        const int bidx = m0 >> 9;
        const int s0 = (m0 + ty * 4) & 511;
        ushort* o = out + (size_t)(bidx * NH + h) * DK * SLEN;
#pragma unroll
        for (int j = 0; j < 4; ++j) {
            uint2 p;
            p.x = pack_bf16(acc[0][j] + bb4[j], acc[1][j] + bb4[j]);
            p.y = pack_bf16(acc[2][j] + bb4[j], acc[3][j] + bb4[j]);
            *(uint2*)&o[(size_t)(tx * 4 + j) * SLEN + s0] = p;
        }
    }
}

// ---------------------------------------------------------------------------
// Bias: bias[b,h,q,k] = sum_c dtw[b,c,q,k]*Wd[h,c] + bd[h]
// Staged into the attn region of d_out (attn kernel reads then overwrites).
// ---------------------------------------------------------------------------
__global__ __launch_bounds__(512) void bias_kernel(
    const float* __restrict__ dtw, const float* __restrict__ Wd,
    const float* __restrict__ bd, float* __restrict__ bias_out)
{
    __shared__ float wdl[NH * DC];
    __shared__ float bdl[NH];
    const int k = threadIdx.x;
    const int q = blockIdx.x;
    const int b = blockIdx.y;
    if (k < NH * DC) wdl[k] = Wd[k];
    if (k < NH) bdl[k] = bd[k];
    __syncthreads();

    float acc[NH];
#pragma unroll
    for (int h = 0; h < NH; ++h) acc[h] = bdl[h];

    const float* p = dtw + ((size_t)b * DC * SLEN + q) * SLEN + k;
#pragma unroll
    for (int c = 0; c < DC; ++c) {
        const float x = p[(size_t)c * SLEN * SLEN];
#pragma unroll
        for (int h = 0; h < NH; ++h) acc[h] += x * wdl[h * DC + c];
    }
#pragma unroll
    for (int h = 0; h < NH; ++h)
        bias_out[((size_t)(b * NH + h) * SLEN + q) * SLEN + k] = acc[h];
}

// ---------------------------------------------------------------------------
// MFMA attention. Block = 4 waves, 64 q-rows per block (16 per wave).
// Swapped QK^T: D = K_tile x Q^T so lane holds S[k=...][q=lane&15]:
//   per lane: q = lane&15, k = 16*kt + 4*(lane>>4) + reg  (32 tiles -> 128 k).
// Softmax = in-lane reduce over 128 + shfl_xor(16) + shfl_xor(32).
// P (unnormalized exp) -> bf16 -> per-wave XOR-swizzled LDS -> A-frags for PV.
// V consumed from transposed layout [bh][d][s] so B-frags are contiguous.
// No __syncthreads in this kernel.
// ---------------------------------------------------------------------------
__global__ __launch_bounds__(256, 2) void attn_mfma(
    const ushort* __restrict__ qb, const ushort* __restrict__ kb,
    const ushort* __restrict__ vt, float* __restrict__ attn,
    float* __restrict__ concat)
{
    __shared__ ushort P_lds[4][16][512];   // 64 KB, per-wave private

    const int tid = threadIdx.x;
    const int wave = tid >> 6;
    const int lane = tid & 63;
    const int lq = lane & 15;
    const int lg = lane >> 4;
    const int qt = blockIdx.x;
    const int h = blockIdx.y, b = blockIdx.z;
    const int bh = b * NH + h;
    const int q0 = qt * 64 + wave * 16;

    const ushort* qptr = qb + ((size_t)bh * SLEN + q0) * DK;
    const ushort* kptr = kb + (size_t)bh * SLEN * DK;
    const ushort* vptr = vt + (size_t)bh * DK * SLEN;
    float* attn_b = attn + ((size_t)bh * SLEN + q0) * SLEN;

    // Q B-fragments: B[d][q]: lane holds q=lq, d = lg*8+j (+32 for chunk 1)
    const short8 qf0 = *(const short8*)&qptr[(size_t)lq * DK + lg * 8];
    const short8 qf1 = *(const short8*)&qptr[(size_t)lq * DK + lg * 8 + 32];

    const float* bias_row = attn_b + (size_t)lq * SLEN;

    f32x4 sc[32];
    // ---- QK^T (swapped) + scale + bias ----
#pragma unroll
    for (int kt = 0; kt < 32; ++kt) {
        const short8 a0 = *(const short8*)&kptr[(size_t)(kt * 16 + lq) * DK + lg * 8];
        const short8 a1 = *(const short8*)&kptr[(size_t)(kt * 16 + lq) * DK + lg * 8 + 32];
        f32x4 c = {0.f, 0.f, 0.f, 0.f};
        c = __builtin_amdgcn_mfma_f32_16x16x32_bf16(a0, qf0, c, 0, 0, 0);
        c = __builtin_amdgcn_mfma_f32_16x16x32_bf16(a1, qf1, c, 0, 0, 0);
        const f32x4 bias4 = *(const f32x4*)&bias_row[kt * 16 + lg * 4];
        sc[kt] = c * 0.125f + bias4;
    }

    // ---- softmax (row q = lq lives in this lane + lanes lane^16, lane^32) ----
    float m = -1e30f;
#pragma unroll
    for (int kt = 0; kt < 32; ++kt)
        m = fmaxf(m, fmaxf(fmaxf(sc[kt][0], sc[kt][1]), fmaxf(sc[kt][2], sc[kt][3])));
    m = fmaxf(m, __shfl_xor(m, 16));
    m = fmaxf(m, __shfl_xor(m, 32));

    float sum = 0.f;
#pragma unroll
    for (int kt = 0; kt < 32; ++kt) {
        f32x4 e;
        e[0] = __expf(sc[kt][0] - m);
        e[1] = __expf(sc[kt][1] - m);
        e[2] = __expf(sc[kt][2] - m);
        e[3] = __expf(sc[kt][3] - m);
        sum += (e[0] + e[1]) + (e[2] + e[3]);
        sc[kt] = e;
    }
    sum += __shfl_xor(sum, 16);
    sum += __shfl_xor(sum, 32);
    const float inv = 1.0f / sum;

    // ---- write attn (normalized) + stage P (unnormalized bf16) in LDS ----
    char* pbase = (char*)&P_lds[wave][0][0];
    const unsigned swz = (unsigned)((lq & 7) << 4);
#pragma unroll
    for (int kt = 0; kt < 32; ++kt) {
        const f32x4 e = sc[kt];
        f32x4 a4 = e * inv;
        *(f32x4*)&attn_b[(size_t)lq * SLEN + kt * 16 + lg * 4] = a4;
        uint2 pk;
        pk.x = pack_bf16(e[0], e[1]);
        pk.y = pack_bf16(e[2], e[3]);
        const unsigned byte = (unsigned)(lq * 1024 + kt * 32 + lg * 8) ^ swz;
        *(uint2*)(pbase + byte) = pk;
    }
    // wave-private LDS RAW fence (other lanes' writes -> this lane's reads)
    asm volatile("s_waitcnt lgkmcnt(0)" ::: "memory");
    __builtin_amdgcn_sched_barrier(0);

    // ---- PV: out[16q x 64d] = P[16q x 512k] @ V[512k x 64d] ----
    f32x4 oacc[4] = {{0.f,0.f,0.f,0.f},{0.f,0.f,0.f,0.f},{0.f,0.f,0.f,0.f},{0.f,0.f,0.f,0.f}};
#pragma unroll
    for (int c = 0; c < 16; ++c) {
        const unsigned byteA = (unsigned)(lq * 1024 + c * 64 + lg * 16) ^ swz;
        const short8 pa = *(const short8*)(pbase + byteA);
#pragma unroll
        for (int dt = 0; dt < 4; ++dt) {
            const short8 vb8 = *(const short8*)&vptr[(size_t)(dt * 16 + lq) * SLEN + c * 32 + lg * 8];
            oacc[dt] = __builtin_amdgcn_mfma_f32_16x16x32_bf16(pa, vb8, oacc[dt], 0, 0, 0);
        }
    }

    // ---- scale by 1/sum and store to concat [b][s][h*64+d] ----
    float* cbase = concat + ((size_t)(b * SLEN + q0)) * DM + h * 64;
#pragma unroll
    for (int r = 0; r < 4; ++r) {
        const float iv = __shfl(inv, lg * 4 + r);
#pragma unroll
        for (int dt = 0; dt < 4; ++dt) {
            cbase[(size_t)(lg * 4 + r) * DM + dt * 16 + lq] = oacc[dt][r] * iv;
        }
    }
}

// ---------------------------------------------------------------------------
extern "C" void kernel_launch(void* const* d_in, const int* in_sizes, int n_in,
                              void* d_out, int out_size, void* d_ws, size_t ws_size,
                              hipStream_t stream)
{
    const float* Q   = (const float*)d_in[0];
    const float* K   = (const float*)d_in[1];
    const float* V   = (const float*)d_in[2];
    const float* dtw = (const float*)d_in[4];
    const float* Wq  = (const float*)d_in[5];
    const float* bq  = (const float*)d_in[6];
    const float* Wk  = (const float*)d_in[7];
    const float* bk  = (const float*)d_in[8];
    const float* Wv  = (const float*)d_in[9];
    const float* bv  = (const float*)d_in[10];
    const float* Wd  = (const float*)d_in[11];
    const float* bd  = (const float*)d_in[12];
    const float* Wo  = (const float*)d_in[13];
    const float* bo  = (const float*)d_in[14];

    float* out  = (float*)d_out;                       // [16,512,512]
    float* attn = out + (size_t)BS * SLEN * DM;        // [16,8,512,512]

    const size_t PHS = (size_t)BS * NH * SLEN * DK;    // 4,194,304 elements
    ushort* qb = (ushort*)d_ws;
    ushort* kb = qb + PHS;
    ushort* vt = kb + PHS;
    float*  cb = (float*)(vt + PHS);                   // concat fp32 [16,512,512]

    const dim3 gemm_grid(8, 128);

    gemm512<<<gemm_grid, 256, 0, stream>>>(Q, Wq, bq, qb, 1);
    gemm512<<<gemm_grid, 256, 0, stream>>>(K, Wk, bk, kb, 1);
    gemm512<<<gemm_grid, 256, 0, stream>>>(V, Wv, bv, vt, 2);

    bias_kernel<<<dim3(SLEN, BS), 512, 0, stream>>>(dtw, Wd, bd, attn);

    attn_mfma<<<dim3(SLEN / 64, NH, BS), 256, 0, stream>>>(qb, kb, vt, attn, cb);

    gemm512<<<gemm_grid, 256, 0, stream>>>(cb, Wo, bo, out, 0);
}

// Round 4
// 269.478 us; speedup vs baseline: 2.7193x; 1.7834x over previous
//
#include <hip/hip_runtime.h>
#include <hip/hip_bf16.h>
#include <cstddef>
#include <cstdint>

#define BS   16
#define SLEN 512
#define DM   512
#define NH   8
#define DK   64
#define DC   21

typedef __attribute__((ext_vector_type(8))) short short8;   // 8 bf16 = 4 VGPR
typedef __attribute__((ext_vector_type(4))) float f32x4;

__device__ inline unsigned pack_bf16(float a, float b) {
    unsigned ua = __builtin_bit_cast(unsigned, a);
    unsigned ub = __builtin_bit_cast(unsigned, b);
    ua = (ua + 0x7fffu + ((ua >> 16) & 1u)) >> 16;          // RNE
    ub = (ub + 0x7fffu + ((ub >> 16) & 1u)) >> 16;
    return ua | (ub << 16);
}

// 2 floats -> packed bf16x2 (RNE)
__device__ inline unsigned cvt2(float a, float b) { return pack_bf16(a, b); }

// ---------------------------------------------------------------------------
// bf16 MFMA GEMM: C[m][n] = sum_k X[m][k]*W[n][k] + bias[n]
// X fp32 [Mx512], W fp32 [512x512], converted to bf16 on the fly.
// BM=64, BN=128, BK=64; 256 threads (4 waves, 2x2), wave owns 32x64.
// LDS tiles [row][64 bf16] (128B rows), 16B-slot XOR swizzle: slot ^= row&7.
// mode 0: fp32 out[m*512+n]
// mode 1: bf16 per-head out[bh][s][64]
// mode 2: bf16 transposed out[bh][64][s]
// ---------------------------------------------------------------------------
__global__ __launch_bounds__(256) void gemm_bf16(
    const float* __restrict__ X, const float* __restrict__ W,
    const float* __restrict__ bias, void* __restrict__ outv, int mode)
{
    __shared__ alignas(16) ushort Atile[64 * 64];    // 8 KB
    __shared__ alignas(16) ushort Btile[128 * 64];   // 16 KB

    const int tid = threadIdx.x;
    const int wave = tid >> 6, lane = tid & 63;
    const int lq = lane & 15, lg = lane >> 4;
    const int wr = wave >> 1, wc = wave & 1;
    const int m0 = blockIdx.x * 64;
    const int n0 = blockIdx.y * 128;

    f32x4 acc[2][4];
#pragma unroll
    for (int i = 0; i < 2; ++i)
#pragma unroll
        for (int j = 0; j < 4; ++j) acc[i][j] = (f32x4){0.f, 0.f, 0.f, 0.f};

    // staged globals: A 2 pairs (row,colpair), B 4 pairs; each pair = 2 float4
    float4 pa[2][2], pb[4][2];

#define LOAD_A(K0)                                                          \
    _Pragma("unroll")                                                       \
    for (int i = 0; i < 2; ++i) {                                           \
        const int P = tid + 256 * i;                                        \
        const int row = P >> 3, cp = P & 7;                                 \
        const float4* s = (const float4*)&X[(size_t)(m0 + row) * 512 + (K0) + cp * 8]; \
        pa[i][0] = s[0]; pa[i][1] = s[1];                                   \
    }
#define LOAD_B(K0)                                                          \
    _Pragma("unroll")                                                       \
    for (int i = 0; i < 4; ++i) {                                           \
        const int P = tid + 256 * i;                                        \
        const int row = P >> 3, cp = P & 7;                                 \
        const float4* s = (const float4*)&W[(size_t)(n0 + row) * 512 + (K0) + cp * 8]; \
        pb[i][0] = s[0]; pb[i][1] = s[1];                                   \
    }

    LOAD_A(0)
    LOAD_B(0)

    for (int it = 0; it < 8; ++it) {
        __syncthreads();   // previous compute done; LDS free
        // convert + write staged tiles (swizzled)
#pragma unroll
        for (int i = 0; i < 2; ++i) {
            const int P = tid + 256 * i;
            const int row = P >> 3, cp = P & 7;
            uint4 w;
            w.x = cvt2(pa[i][0].x, pa[i][0].y);
            w.y = cvt2(pa[i][0].z, pa[i][0].w);
            w.z = cvt2(pa[i][1].x, pa[i][1].y);
            w.w = cvt2(pa[i][1].z, pa[i][1].w);
            *(uint4*)((char*)Atile + row * 128 + 16 * (cp ^ (row & 7))) = w;
        }
#pragma unroll
        for (int i = 0; i < 4; ++i) {
            const int P = tid + 256 * i;
            const int row = P >> 3, cp = P & 7;
            uint4 w;
            w.x = cvt2(pb[i][0].x, pb[i][0].y);
            w.y = cvt2(pb[i][0].z, pb[i][0].w);
            w.z = cvt2(pb[i][1].x, pb[i][1].y);
            w.w = cvt2(pb[i][1].z, pb[i][1].w);
            *(uint4*)((char*)Btile + row * 128 + 16 * (cp ^ (row & 7))) = w;
        }
        __syncthreads();

        // prefetch next K-tile (hides under MFMA below)
        if (it < 7) {
            const int kn = (it + 1) * 64;
            LOAD_A(kn)
            LOAD_B(kn)
        }

        // fragments + MFMA
        short8 af[2][2], bfr[4][2];
#pragma unroll
        for (int mi = 0; mi < 2; ++mi)
#pragma unroll
            for (int kh = 0; kh < 2; ++kh) {
                const int row = wr * 32 + mi * 16 + lq;
                af[mi][kh] = *(const short8*)((const char*)Atile + row * 128 +
                                              16 * ((kh * 4 + lg) ^ (row & 7)));
            }
#pragma unroll
        for (int ni = 0; ni < 4; ++ni)
#pragma unroll
            for (int kh = 0; kh < 2; ++kh) {
                const int row = wc * 64 + ni * 16 + lq;
                bfr[ni][kh] = *(const short8*)((const char*)Btile + row * 128 +
                                               16 * ((kh * 4 + lg) ^ (row & 7)));
            }
#pragma unroll
        for (int kh = 0; kh < 2; ++kh)
#pragma unroll
            for (int mi = 0; mi < 2; ++mi)
#pragma unroll
                for (int ni = 0; ni < 4; ++ni)
                    acc[mi][ni] = __builtin_amdgcn_mfma_f32_16x16x32_bf16(
                        af[mi][kh], bfr[ni][kh], acc[mi][ni], 0, 0, 0);
    }
#undef LOAD_A
#undef LOAD_B

    // ---- epilogue ----
    if (mode == 0) {
        float* out = (float*)outv;
#pragma unroll
        for (int mi = 0; mi < 2; ++mi) {
            const int mb = m0 + wr * 32 + mi * 16 + lg * 4;
#pragma unroll
            for (int ni = 0; ni < 4; ++ni) {
                const int n = n0 + wc * 64 + ni * 16 + lq;
                const float bb = bias[n];
#pragma unroll
                for (int r = 0; r < 4; ++r)
                    out[(size_t)(mb + r) * 512 + n] = acc[mi][ni][r] + bb;
            }
        }
    } else if (mode == 1) {
        ushort* out = (ushort*)outv;
#pragma unroll
        for (int mi = 0; mi < 2; ++mi) {
            const int mb = m0 + wr * 32 + mi * 16 + lg * 4;
#pragma unroll
            for (int ni = 0; ni < 4; ++ni) {
                const int n = n0 + wc * 64 + ni * 16 + lq;
                const int h = n >> 6, d = n & 63;
                const float bb = bias[n];
#pragma unroll
                for (int r = 0; r < 4; ++r) {
                    const int m = mb + r;
                    const int bidx = m >> 9, s = m & 511;
                    const float v = acc[mi][ni][r] + bb;
                    out[((size_t)(bidx * NH + h) * SLEN + s) * DK + d] =
                        (ushort)(pack_bf16(v, 0.f) & 0xffffu);
                }
            }
        }
    } else {
        ushort* out = (ushort*)outv;
#pragma unroll
        for (int mi = 0; mi < 2; ++mi) {
            const int mb = m0 + wr * 32 + mi * 16 + lg * 4;
            const int bidx = mb >> 9, s0 = mb & 511;
#pragma unroll
            for (int ni = 0; ni < 4; ++ni) {
                const int n = n0 + wc * 64 + ni * 16 + lq;
                const int h = n >> 6, d = n & 63;
                const float bb = bias[n];
                uint2 pk;
                pk.x = cvt2(acc[mi][ni][0] + bb, acc[mi][ni][1] + bb);
                pk.y = cvt2(acc[mi][ni][2] + bb, acc[mi][ni][3] + bb);
                *(uint2*)&out[((size_t)(bidx * NH + h) * DK + d) * SLEN + s0] = pk;
            }
        }
    }
}

// ---------------------------------------------------------------------------
// Bias: bias[b,h,q,k] = sum_c dtw[b,c,q,k]*Wd[h,c] + bd[h]
// Staged into the attn region of d_out (attn kernel reads then overwrites).
// ---------------------------------------------------------------------------
__global__ __launch_bounds__(512) void bias_kernel(
    const float* __restrict__ dtw, const float* __restrict__ Wd,
    const float* __restrict__ bd, float* __restrict__ bias_out)
{
    __shared__ float wdl[NH * DC];
    __shared__ float bdl[NH];
    const int k = threadIdx.x;
    const int q = blockIdx.x;
    const int b = blockIdx.y;
    if (k < NH * DC) wdl[k] = Wd[k];
    if (k < NH) bdl[k] = bd[k];
    __syncthreads();

    float acc[NH];
#pragma unroll
    for (int h = 0; h < NH; ++h) acc[h] = bdl[h];

    const float* p = dtw + ((size_t)b * DC * SLEN + q) * SLEN + k;
#pragma unroll
    for (int c = 0; c < DC; ++c) {
        const float x = p[(size_t)c * SLEN * SLEN];
#pragma unroll
        for (int h = 0; h < NH; ++h) acc[h] += x * wdl[h * DC + c];
    }
#pragma unroll
    for (int h = 0; h < NH; ++h)
        bias_out[((size_t)(b * NH + h) * SLEN + q) * SLEN + k] = acc[h];
}

// ---------------------------------------------------------------------------
// MFMA attention (unchanged from round 2).
// ---------------------------------------------------------------------------
__global__ __launch_bounds__(256, 2) void attn_mfma(
    const ushort* __restrict__ qb, const ushort* __restrict__ kb,
    const ushort* __restrict__ vt, float* __restrict__ attn,
    float* __restrict__ concat)
{
    __shared__ ushort P_lds[4][16][512];   // 64 KB, per-wave private

    const int tid = threadIdx.x;
    const int wave = tid >> 6;
    const int lane = tid & 63;
    const int lq = lane & 15;
    const int lg = lane >> 4;
    const int qt = blockIdx.x;
    const int h = blockIdx.y, b = blockIdx.z;
    const int bh = b * NH + h;
    const int q0 = qt * 64 + wave * 16;

    const ushort* qptr = qb + ((size_t)bh * SLEN + q0) * DK;
    const ushort* kptr = kb + (size_t)bh * SLEN * DK;
    const ushort* vptr = vt + (size_t)bh * DK * SLEN;
    float* attn_b = attn + ((size_t)bh * SLEN + q0) * SLEN;

    const short8 qf0 = *(const short8*)&qptr[(size_t)lq * DK + lg * 8];
    const short8 qf1 = *(const short8*)&qptr[(size_t)lq * DK + lg * 8 + 32];

    const float* bias_row = attn_b + (size_t)lq * SLEN;

    f32x4 sc[32];
#pragma unroll
    for (int kt = 0; kt < 32; ++kt) {
        const short8 a0 = *(const short8*)&kptr[(size_t)(kt * 16 + lq) * DK + lg * 8];
        const short8 a1 = *(const short8*)&kptr[(size_t)(kt * 16 + lq) * DK + lg * 8 + 32];
        f32x4 c = {0.f, 0.f, 0.f, 0.f};
        c = __builtin_amdgcn_mfma_f32_16x16x32_bf16(a0, qf0, c, 0, 0, 0);
        c = __builtin_amdgcn_mfma_f32_16x16x32_bf16(a1, qf1, c, 0, 0, 0);
        const f32x4 bias4 = *(const f32x4*)&bias_row[kt * 16 + lg * 4];
        sc[kt] = c * 0.125f + bias4;
    }

    float m = -1e30f;
#pragma unroll
    for (int kt = 0; kt < 32; ++kt)
        m = fmaxf(m, fmaxf(fmaxf(sc[kt][0], sc[kt][1]), fmaxf(sc[kt][2], sc[kt][3])));
    m = fmaxf(m, __shfl_xor(m, 16));
    m = fmaxf(m, __shfl_xor(m, 32));

    float sum = 0.f;
#pragma unroll
    for (int kt = 0; kt < 32; ++kt) {
        f32x4 e;
        e[0] = __expf(sc[kt][0] - m);
        e[1] = __expf(sc[kt][1] - m);
        e[2] = __expf(sc[kt][2] - m);
        e[3] = __expf(sc[kt][3] - m);
        sum += (e[0] + e[1]) + (e[2] + e[3]);
        sc[kt] = e;
    }
    sum += __shfl_xor(sum, 16);
    sum += __shfl_xor(sum, 32);
    const float inv = 1.0f / sum;

    char* pbase = (char*)&P_lds[wave][0][0];
    const unsigned swz = (unsigned)((lq & 7) << 4);
#pragma unroll
    for (int kt = 0; kt < 32; ++kt) {
        const f32x4 e = sc[kt];
        f32x4 a4 = e * inv;
        *(f32x4*)&attn_b[(size_t)lq * SLEN + kt * 16 + lg * 4] = a4;
        uint2 pk;
        pk.x = pack_bf16(e[0], e[1]);
        pk.y = pack_bf16(e[2], e[3]);
        const unsigned byte = (unsigned)(lq * 1024 + kt * 32 + lg * 8) ^ swz;
        *(uint2*)(pbase + byte) = pk;
    }
    asm volatile("s_waitcnt lgkmcnt(0)" ::: "memory");
    __builtin_amdgcn_sched_barrier(0);

    f32x4 oacc[4] = {{0.f,0.f,0.f,0.f},{0.f,0.f,0.f,0.f},{0.f,0.f,0.f,0.f},{0.f,0.f,0.f,0.f}};
#pragma unroll
    for (int c = 0; c < 16; ++c) {
        const unsigned byteA = (unsigned)(lq * 1024 + c * 64 + lg * 16) ^ swz;
        const short8 pa = *(const short8*)(pbase + byteA);
#pragma unroll
        for (int dt = 0; dt < 4; ++dt) {
            const short8 vb8 = *(const short8*)&vptr[(size_t)(dt * 16 + lq) * SLEN + c * 32 + lg * 8];
            oacc[dt] = __builtin_amdgcn_mfma_f32_16x16x32_bf16(pa, vb8, oacc[dt], 0, 0, 0);
        }
    }

    float* cbase = concat + ((size_t)(b * SLEN + q0)) * DM + h * 64;
#pragma unroll
    for (int r = 0; r < 4; ++r) {
        const float iv = __shfl(inv, lg * 4 + r);
#pragma unroll
        for (int dt = 0; dt < 4; ++dt) {
            cbase[(size_t)(lg * 4 + r) * DM + dt * 16 + lq] = oacc[dt][r] * iv;
        }
    }
}

// ---------------------------------------------------------------------------
extern "C" void kernel_launch(void* const* d_in, const int* in_sizes, int n_in,
                              void* d_out, int out_size, void* d_ws, size_t ws_size,
                              hipStream_t stream)
{
    const float* Q   = (const float*)d_in[0];
    const float* K   = (const float*)d_in[1];
    const float* V   = (const float*)d_in[2];
    const float* dtw = (const float*)d_in[4];
    const float* Wq  = (const float*)d_in[5];
    const float* bq  = (const float*)d_in[6];
    const float* Wk  = (const float*)d_in[7];
    const float* bk  = (const float*)d_in[8];
    const float* Wv  = (const float*)d_in[9];
    const float* bv  = (const float*)d_in[10];
    const float* Wd  = (const float*)d_in[11];
    const float* bd  = (const float*)d_in[12];
    const float* Wo  = (const float*)d_in[13];
    const float* bo  = (const float*)d_in[14];

    float* out  = (float*)d_out;                       // [16,512,512]
    float* attn = out + (size_t)BS * SLEN * DM;        // [16,8,512,512]

    const size_t PHS = (size_t)BS * NH * SLEN * DK;    // 4,194,304 elements
    ushort* qb = (ushort*)d_ws;
    ushort* kb = qb + PHS;
    ushort* vt = kb + PHS;
    float*  cb = (float*)(vt + PHS);                   // concat fp32 [16,512,512]

    const dim3 gemm_grid(128, 4);                      // m-tiles x n-tiles

    gemm_bf16<<<gemm_grid, 256, 0, stream>>>(Q, Wq, bq, qb, 1);
    gemm_bf16<<<gemm_grid, 256, 0, stream>>>(K, Wk, bk, kb, 1);
    gemm_bf16<<<gemm_grid, 256, 0, stream>>>(V, Wv, bv, vt, 2);

    bias_kernel<<<dim3(SLEN, BS), 512, 0, stream>>>(dtw, Wd, bd, attn);

    attn_mfma<<<dim3(SLEN / 64, NH, BS), 256, 0, stream>>>(qb, kb, vt, attn, cb);

    gemm_bf16<<<gemm_grid, 256, 0, stream>>>(cb, Wo, bo, out, 0);
}